// Round 1
// baseline (987.239 us; speedup 1.0000x reference)
//
#include <hip/hip_runtime.h>

#define N_NODES 100000
#define N_EDGES 1600000
#define IN_F 128
#define H_F 64

// ---------------- degree ----------------
__global__ void deg_kernel(const int* __restrict__ dst, int* __restrict__ indeg, int E) {
    int i = blockIdx.x * blockDim.x + threadIdx.x;
    if (i < E) atomicAdd(&indeg[dst[i]], 1);
}

__global__ void dinv_kernel(const int* __restrict__ indeg,
                            float* __restrict__ dinv1, float* __restrict__ dinv2, int N) {
    int i = blockIdx.x * blockDim.x + threadIdx.x;
    if (i < N) {
        int d = indeg[i];
        dinv1[i] = rsqrtf((float)(d + 1));            // self-loop included
        dinv2[i] = (d > 0) ? rsqrtf((float)d) : 0.0f; // no self-loop
    }
}

// ---------------- GEMM: x = in_feat @ W1  [N,128]x[128,64] ----------------
__global__ __launch_bounds__(256) void gemm_kernel(const float* __restrict__ A,
                                                   const float* __restrict__ W,
                                                   float* __restrict__ X, int N) {
    __shared__ float Ws[IN_F * H_F]; // 32 KB
    for (int i = threadIdx.x; i < IN_F * H_F / 4; i += 256) {
        reinterpret_cast<float4*>(Ws)[i] = reinterpret_cast<const float4*>(W)[i];
    }
    __syncthreads();

    int gtid   = blockIdx.x * blockDim.x + threadIdx.x;
    int wid    = gtid >> 6;
    int lane   = threadIdx.x & 63;
    int nwaves = (gridDim.x * blockDim.x) >> 6;

    for (int node = wid; node < N; node += nwaves) {
        const float4* row = reinterpret_cast<const float4*>(A + (size_t)node * IN_F);
        float acc = 0.0f;
        #pragma unroll
        for (int k4 = 0; k4 < IN_F / 4; ++k4) {
            float4 r = row[k4]; // wave-uniform broadcast load
            acc += r.x * Ws[(k4 * 4 + 0) * H_F + lane];
            acc += r.y * Ws[(k4 * 4 + 1) * H_F + lane];
            acc += r.z * Ws[(k4 * 4 + 2) * H_F + lane];
            acc += r.w * Ws[(k4 * 4 + 3) * H_F + lane];
        }
        X[(size_t)node * H_F + lane] = acc;
    }
}

// ---------------- self-loop init: h1 = x * dinv1^2 ----------------
__global__ void selfloop_kernel(const float* __restrict__ X, const float* __restrict__ dinv1,
                                float* __restrict__ H, int total) {
    int i = blockIdx.x * blockDim.x + threadIdx.x;
    if (i < total) {
        int node = i >> 6;
        float d = dinv1[node];
        H[i] = X[i] * d * d;
    }
}

// ---------------- out init: out = alpha0 * h1 ----------------
__global__ void scale_kernel(const float* __restrict__ H1, const float* __restrict__ alphas,
                             float* __restrict__ out, int total) {
    int i = blockIdx.x * blockDim.x + threadIdx.x;
    if (i < total) {
        float e0 = expf(alphas[0]), e1 = expf(alphas[1]);
        float a0 = e0 / (e0 + e1);
        out[i] = H1[i] * a0;
    }
}

// ---------------- edge scatter: Hout[dst] += scale * Xin[src]*dinv[s]*dinv[d] ----------------
// one wave per edge, lane = feature. alphas==nullptr -> scale 1 (prop1);
// else scale = softmax(alphas)[1] (prop2 fused with alpha-combine).
__global__ void prop_kernel(const int* __restrict__ src, const int* __restrict__ dst,
                            const float* __restrict__ dinv,
                            const float* __restrict__ Xin, float* __restrict__ Hout,
                            const float* __restrict__ alphas, int E) {
    int gtid = blockIdx.x * blockDim.x + threadIdx.x;
    int lane = gtid & 63;
    int wid  = gtid >> 6;
    int nw   = (gridDim.x * blockDim.x) >> 6;

    float scale = 1.0f;
    if (alphas) {
        float e0 = expf(alphas[0]), e1 = expf(alphas[1]);
        scale = e1 / (e0 + e1);
    }

    for (int e = wid; e < E; e += nw) {
        int s = src[e], d = dst[e];
        float norm = dinv[s] * dinv[d] * scale;
        float v = Xin[(size_t)s * H_F + lane] * norm;
        atomicAdd(&Hout[(size_t)d * H_F + lane], v);
    }
}

extern "C" void kernel_launch(void* const* d_in, const int* in_sizes, int n_in,
                              void* d_out, int out_size, void* d_ws, size_t ws_size,
                              hipStream_t stream) {
    const int*   edge_index = (const int*)d_in[0];   // [2, E]
    const float* in_feat    = (const float*)d_in[1]; // [N, 128]
    const float* W1         = (const float*)d_in[2]; // [128, 64]
    const float* alphas     = (const float*)d_in[3]; // [2]
    float*       out        = (float*)d_out;         // [N, 64]

    const int* src = edge_index;
    const int* dst = edge_index + N_EDGES;

    // workspace layout
    char* ws = (char*)d_ws;
    size_t featBytes = (size_t)N_NODES * H_F * sizeof(float); // 25.6 MB
    float* X     = (float*)(ws);
    float* H1    = (float*)(ws + featBytes);
    float* dinv1 = (float*)(ws + 2 * featBytes);
    float* dinv2 = (float*)(ws + 2 * featBytes + (size_t)N_NODES * sizeof(float));
    int*   indeg = (int*)  (ws + 2 * featBytes + (size_t)2 * N_NODES * sizeof(float));

    hipMemsetAsync(indeg, 0, (size_t)N_NODES * sizeof(int), stream);

    // degrees
    deg_kernel<<<(N_EDGES + 255) / 256, 256, 0, stream>>>(dst, indeg, N_EDGES);
    dinv_kernel<<<(N_NODES + 255) / 256, 256, 0, stream>>>(indeg, dinv1, dinv2, N_NODES);

    // x = in_feat @ W1
    gemm_kernel<<<1024, 256, 0, stream>>>(in_feat, W1, X, N_NODES);

    // prop 1 (with self loops): h1 = x*dinv1^2 + scatter
    int total = N_NODES * H_F;
    selfloop_kernel<<<(total + 255) / 256, 256, 0, stream>>>(X, dinv1, H1, total);
    prop_kernel<<<2048, 256, 0, stream>>>(src, dst, dinv1, X, H1, nullptr, N_EDGES);

    // out = alpha0*h1, then prop 2 (no self loops) accumulates alpha1*msg into out
    scale_kernel<<<(total + 255) / 256, 256, 0, stream>>>(H1, alphas, out, total);
    prop_kernel<<<2048, 256, 0, stream>>>(src, dst, dinv2, H1, out, alphas, N_EDGES);
}

// Round 2
// 430.506 us; speedup vs baseline: 2.2932x; 2.2932x over previous
//
#include <hip/hip_runtime.h>

#define N_NODES 100000
#define N_EDGES 1600000
#define IN_F 128
#define H_F 64

// ---------------- degree histogram ----------------
__global__ void deg_kernel(const int* __restrict__ dst, int* __restrict__ indeg, int E) {
    int i = blockIdx.x * blockDim.x + threadIdx.x;
    if (i < E) atomicAdd(&indeg[dst[i]], 1);
}

__global__ void dinv_kernel(const int* __restrict__ indeg,
                            float* __restrict__ dinv1, float* __restrict__ dinv2, int N) {
    int i = blockIdx.x * blockDim.x + threadIdx.x;
    if (i < N) {
        int d = indeg[i];
        dinv1[i] = rsqrtf((float)(d + 1));            // self-loop included
        dinv2[i] = (d > 0) ? rsqrtf((float)d) : 0.0f; // no self-loop
    }
}

// ---------------- exclusive scan of indeg (1024 elems / block) ----------------
__global__ void scanA_kernel(const int* __restrict__ indeg, int* __restrict__ blockSums, int N) {
    __shared__ int sd[256];
    int tid = threadIdx.x;
    int base = blockIdx.x * 1024 + tid * 4;
    int s = 0;
    #pragma unroll
    for (int j = 0; j < 4; ++j) s += (base + j < N) ? indeg[base + j] : 0;
    sd[tid] = s;
    __syncthreads();
    for (int off = 128; off > 0; off >>= 1) {
        if (tid < off) sd[tid] += sd[tid + off];
        __syncthreads();
    }
    if (tid == 0) blockSums[blockIdx.x] = sd[0];
}

__global__ void scanB_kernel(const int* __restrict__ blockSums, int* __restrict__ blockOffsets, int nb) {
    __shared__ int sd[256];
    int tid = threadIdx.x;
    int v = (tid < nb) ? blockSums[tid] : 0;
    sd[tid] = v;
    __syncthreads();
    for (int off = 1; off < 256; off <<= 1) {
        int t = (tid >= off) ? sd[tid - off] : 0;
        __syncthreads();
        sd[tid] += t;
        __syncthreads();
    }
    if (tid < nb) blockOffsets[tid] = sd[tid] - v; // exclusive
}

__global__ void scanC_kernel(const int* __restrict__ indeg, const int* __restrict__ blockOffsets,
                             int* __restrict__ offsets, int* __restrict__ cursor, int N, int E) {
    __shared__ int sd[256];
    int tid = threadIdx.x;
    int base = blockIdx.x * 1024 + tid * 4;
    int v[4], s = 0;
    #pragma unroll
    for (int j = 0; j < 4; ++j) { v[j] = (base + j < N) ? indeg[base + j] : 0; s += v[j]; }
    sd[tid] = s;
    __syncthreads();
    for (int off = 1; off < 256; off <<= 1) {
        int t = (tid >= off) ? sd[tid - off] : 0;
        __syncthreads();
        sd[tid] += t;
        __syncthreads();
    }
    int ex = blockOffsets[blockIdx.x] + sd[tid] - s;
    #pragma unroll
    for (int j = 0; j < 4; ++j) {
        if (base + j < N) { offsets[base + j] = ex; cursor[base + j] = ex; ex += v[j]; }
    }
    if (blockIdx.x == 0 && tid == 0) offsets[N] = E; // sum(indeg) == E
}

// ---------------- bucket: CSR adjacency (src list sorted by dst) ----------------
__global__ void bucket_kernel(const int* __restrict__ src, const int* __restrict__ dst,
                              int* __restrict__ cursor, int* __restrict__ sorted_src, int E) {
    int i = blockIdx.x * blockDim.x + threadIdx.x;
    if (i < E) {
        int p = atomicAdd(&cursor[dst[i]], 1);
        sorted_src[p] = src[i];
    }
}

// ---------------- GEMM: Xs = (in_feat @ W1) * dinv1[node]  ----------------
// 4 nodes per wave: 4 FMAs per LDS read.
__global__ __launch_bounds__(256) void gemm_kernel(const float* __restrict__ A,
                                                   const float* __restrict__ W,
                                                   const float* __restrict__ dinv1,
                                                   float* __restrict__ Xs, int N) {
    __shared__ float Ws[IN_F * H_F]; // 32 KB
    for (int i = threadIdx.x; i < IN_F * H_F / 4; i += 256)
        reinterpret_cast<float4*>(Ws)[i] = reinterpret_cast<const float4*>(W)[i];
    __syncthreads();

    int gtid = blockIdx.x * blockDim.x + threadIdx.x;
    int wid  = gtid >> 6;
    int lane = threadIdx.x & 63;
    int nw   = (gridDim.x * blockDim.x) >> 6;

    for (int n0 = wid * 4; n0 < N; n0 += nw * 4) {
        if (n0 + 3 < N) {
            const float4* r0 = reinterpret_cast<const float4*>(A + (size_t)(n0 + 0) * IN_F);
            const float4* r1 = reinterpret_cast<const float4*>(A + (size_t)(n0 + 1) * IN_F);
            const float4* r2 = reinterpret_cast<const float4*>(A + (size_t)(n0 + 2) * IN_F);
            const float4* r3 = reinterpret_cast<const float4*>(A + (size_t)(n0 + 3) * IN_F);
            float acc0 = 0.f, acc1 = 0.f, acc2 = 0.f, acc3 = 0.f;
            #pragma unroll
            for (int k4 = 0; k4 < IN_F / 4; ++k4) {
                float4 a0 = r0[k4], a1 = r1[k4], a2 = r2[k4], a3 = r3[k4];
                float w0 = Ws[(k4 * 4 + 0) * H_F + lane];
                float w1 = Ws[(k4 * 4 + 1) * H_F + lane];
                float w2 = Ws[(k4 * 4 + 2) * H_F + lane];
                float w3 = Ws[(k4 * 4 + 3) * H_F + lane];
                acc0 += a0.x * w0 + a0.y * w1 + a0.z * w2 + a0.w * w3;
                acc1 += a1.x * w0 + a1.y * w1 + a1.z * w2 + a1.w * w3;
                acc2 += a2.x * w0 + a2.y * w1 + a2.z * w2 + a2.w * w3;
                acc3 += a3.x * w0 + a3.y * w1 + a3.z * w2 + a3.w * w3;
            }
            Xs[(size_t)(n0 + 0) * H_F + lane] = acc0 * dinv1[n0 + 0];
            Xs[(size_t)(n0 + 1) * H_F + lane] = acc1 * dinv1[n0 + 1];
            Xs[(size_t)(n0 + 2) * H_F + lane] = acc2 * dinv1[n0 + 2];
            Xs[(size_t)(n0 + 3) * H_F + lane] = acc3 * dinv1[n0 + 3];
        } else {
            for (int n = n0; n < N; ++n) {
                const float4* r = reinterpret_cast<const float4*>(A + (size_t)n * IN_F);
                float acc = 0.f;
                #pragma unroll
                for (int k4 = 0; k4 < IN_F / 4; ++k4) {
                    float4 a = r[k4];
                    acc += a.x * Ws[(k4 * 4 + 0) * H_F + lane];
                    acc += a.y * Ws[(k4 * 4 + 1) * H_F + lane];
                    acc += a.z * Ws[(k4 * 4 + 2) * H_F + lane];
                    acc += a.w * Ws[(k4 * 4 + 3) * H_F + lane];
                }
                Xs[(size_t)n * H_F + lane] = acc * dinv1[n];
            }
        }
    }
}

// ---------------- prop1 (gather): h1[d] = dinv1[d]*sum(Xs[s]) + Xs[d]*dinv1[d] ----------------
__global__ __launch_bounds__(256) void prop1_kernel(const int* __restrict__ offsets,
                                                    const int* __restrict__ sorted_src,
                                                    const float* __restrict__ Xs,
                                                    const float* __restrict__ dinv1,
                                                    float* __restrict__ h1, int N) {
    int gtid = blockIdx.x * blockDim.x + threadIdx.x;
    int wid  = gtid >> 6;
    int lane = threadIdx.x & 63;
    int nw   = (gridDim.x * blockDim.x) >> 6;

    for (int d = wid; d < N; d += nw) {
        int beg = offsets[d], end = offsets[d + 1];
        float acc = 0.f;
        for (int i0 = beg; i0 < end; i0 += 64) {
            int cnt = end - i0; if (cnt > 64) cnt = 64;
            int s_l = 0;
            if (i0 + lane < end) s_l = sorted_src[i0 + lane];
            int j = 0;
            for (; j + 4 <= cnt; j += 4) {
                int s0 = __shfl(s_l, j + 0), s1 = __shfl(s_l, j + 1);
                int s2 = __shfl(s_l, j + 2), s3 = __shfl(s_l, j + 3);
                float x0 = Xs[(size_t)s0 * H_F + lane];
                float x1 = Xs[(size_t)s1 * H_F + lane];
                float x2 = Xs[(size_t)s2 * H_F + lane];
                float x3 = Xs[(size_t)s3 * H_F + lane];
                acc += x0; acc += x1; acc += x2; acc += x3;
            }
            for (; j < cnt; ++j) {
                int s = __shfl(s_l, j);
                acc += Xs[(size_t)s * H_F + lane];
            }
        }
        float dv = dinv1[d];
        h1[(size_t)d * H_F + lane] = dv * acc + Xs[(size_t)d * H_F + lane] * dv;
    }
}

// ---------------- prop2 (gather) + alpha combine ----------------
// out[d] = a0*h1[d] + a1*dinv2[d]*sum(h1[s]*dinv2[s])
__global__ __launch_bounds__(256) void prop2_kernel(const int* __restrict__ offsets,
                                                    const int* __restrict__ sorted_src,
                                                    const float* __restrict__ h1,
                                                    const float* __restrict__ dinv2,
                                                    const float* __restrict__ alphas,
                                                    float* __restrict__ out, int N) {
    int gtid = blockIdx.x * blockDim.x + threadIdx.x;
    int wid  = gtid >> 6;
    int lane = threadIdx.x & 63;
    int nw   = (gridDim.x * blockDim.x) >> 6;

    float e0 = expf(alphas[0]), e1 = expf(alphas[1]);
    float a0 = e0 / (e0 + e1), a1 = e1 / (e0 + e1);

    for (int d = wid; d < N; d += nw) {
        int beg = offsets[d], end = offsets[d + 1];
        float acc = 0.f;
        for (int i0 = beg; i0 < end; i0 += 64) {
            int cnt = end - i0; if (cnt > 64) cnt = 64;
            int s_l = 0; float w_l = 0.f;
            if (i0 + lane < end) { s_l = sorted_src[i0 + lane]; w_l = dinv2[s_l]; }
            int j = 0;
            for (; j + 4 <= cnt; j += 4) {
                int   s0 = __shfl(s_l, j + 0), s1 = __shfl(s_l, j + 1);
                int   s2 = __shfl(s_l, j + 2), s3 = __shfl(s_l, j + 3);
                float w0 = __shfl(w_l, j + 0), w1 = __shfl(w_l, j + 1);
                float w2 = __shfl(w_l, j + 2), w3 = __shfl(w_l, j + 3);
                float x0 = h1[(size_t)s0 * H_F + lane];
                float x1 = h1[(size_t)s1 * H_F + lane];
                float x2 = h1[(size_t)s2 * H_F + lane];
                float x3 = h1[(size_t)s3 * H_F + lane];
                acc += x0 * w0; acc += x1 * w1; acc += x2 * w2; acc += x3 * w3;
            }
            for (; j < cnt; ++j) {
                int   s = __shfl(s_l, j);
                float w = __shfl(w_l, j);
                acc += h1[(size_t)s * H_F + lane] * w;
            }
        }
        out[(size_t)d * H_F + lane] = a0 * h1[(size_t)d * H_F + lane] + a1 * dinv2[d] * acc;
    }
}

extern "C" void kernel_launch(void* const* d_in, const int* in_sizes, int n_in,
                              void* d_out, int out_size, void* d_ws, size_t ws_size,
                              hipStream_t stream) {
    const int*   edge_index = (const int*)d_in[0];   // [2, E]
    const float* in_feat    = (const float*)d_in[1]; // [N, 128]
    const float* W1         = (const float*)d_in[2]; // [128, 64]
    const float* alphas     = (const float*)d_in[3]; // [2]
    float*       out        = (float*)d_out;         // [N, 64]

    const int* src = edge_index;
    const int* dst = edge_index + N_EDGES;

    // workspace layout
    char* ws = (char*)d_ws;
    size_t featBytes = (size_t)N_NODES * H_F * sizeof(float); // 25.6 MB
    float* Xs     = (float*)(ws);                    // 25.6 MB
    float* h1     = (float*)(ws + featBytes);        // 25.6 MB
    char*  p      = ws + 2 * featBytes;
    int*   sorted = (int*)p;          p += (size_t)N_EDGES * 4;       // 6.4 MB
    int*   offs   = (int*)p;          p += (size_t)(N_NODES + 1) * 4;
    int*   cursor = (int*)p;          p += (size_t)N_NODES * 4;
    int*   indeg  = (int*)p;          p += (size_t)N_NODES * 4;
    float* dinv1  = (float*)p;        p += (size_t)N_NODES * 4;
    float* dinv2  = (float*)p;        p += (size_t)N_NODES * 4;
    int*   bsums  = (int*)p;          p += 256 * 4;
    int*   boffs  = (int*)p;

    const int NB = (N_NODES + 1023) / 1024; // 98 scan blocks

    hipMemsetAsync(indeg, 0, (size_t)N_NODES * sizeof(int), stream);

    deg_kernel<<<(N_EDGES + 255) / 256, 256, 0, stream>>>(dst, indeg, N_EDGES);
    scanA_kernel<<<NB, 256, 0, stream>>>(indeg, bsums, N_NODES);
    scanB_kernel<<<1, 256, 0, stream>>>(bsums, boffs, NB);
    scanC_kernel<<<NB, 256, 0, stream>>>(indeg, boffs, offs, cursor, N_NODES, N_EDGES);
    dinv_kernel<<<(N_NODES + 255) / 256, 256, 0, stream>>>(indeg, dinv1, dinv2, N_NODES);
    bucket_kernel<<<(N_EDGES + 255) / 256, 256, 0, stream>>>(src, dst, cursor, sorted, N_EDGES);

    gemm_kernel<<<1024, 256, 0, stream>>>(in_feat, W1, dinv1, Xs, N_NODES);

    int nblocks = (N_NODES * 64 + 255) / 256; // one wave per node
    prop1_kernel<<<nblocks, 256, 0, stream>>>(offs, sorted, Xs, dinv1, h1, N_NODES);
    prop2_kernel<<<nblocks, 256, 0, stream>>>(offs, sorted, h1, dinv2, alphas, out, N_NODES);
}

// Round 3
// 403.722 us; speedup vs baseline: 2.4453x; 1.0663x over previous
//
#include <hip/hip_runtime.h>

#define N_NODES 100000
#define N_EDGES 1600000
#define IN_F 128
#define H_F 64

#define NBKT 49   // coarse buckets: dst >> 11, 99999>>11 = 48
#define BSH 11
#define EPB 2048  // edges per block in coarse scatter

// ---------------- degree + coarse histogram (fused) ----------------
__global__ __launch_bounds__(256) void hist_kernel(const int* __restrict__ dst,
                                                   int* __restrict__ indeg,
                                                   int* __restrict__ ccnt, int E) {
    __shared__ int lh[NBKT];
    for (int i = threadIdx.x; i < NBKT; i += 256) lh[i] = 0;
    __syncthreads();
    int stride = gridDim.x * blockDim.x;
    for (int i = blockIdx.x * blockDim.x + threadIdx.x; i < E; i += stride) {
        int d = dst[i];
        atomicAdd(&indeg[d], 1);
        atomicAdd(&lh[d >> BSH], 1);
    }
    __syncthreads();
    for (int i = threadIdx.x; i < NBKT; i += 256)
        if (lh[i]) atomicAdd(&ccnt[i], lh[i]);
}

// ---------------- coarse offsets (49 entries, trivial) ----------------
__global__ void scan_coarse_kernel(const int* __restrict__ ccnt,
                                   int* __restrict__ ccur) {
    if (threadIdx.x == 0) {
        int run = 0;
        for (int b = 0; b < NBKT; ++b) { ccur[b] = run; run += ccnt[b]; }
    }
}

// ---------------- exclusive scan of indeg (1024 elems / block) ----------------
__global__ void scanA_kernel(const int* __restrict__ indeg, int* __restrict__ blockSums, int N) {
    __shared__ int sd[256];
    int tid = threadIdx.x;
    int base = blockIdx.x * 1024 + tid * 4;
    int s = 0;
    #pragma unroll
    for (int j = 0; j < 4; ++j) s += (base + j < N) ? indeg[base + j] : 0;
    sd[tid] = s;
    __syncthreads();
    for (int off = 128; off > 0; off >>= 1) {
        if (tid < off) sd[tid] += sd[tid + off];
        __syncthreads();
    }
    if (tid == 0) blockSums[blockIdx.x] = sd[0];
}

__global__ void scanB_kernel(const int* __restrict__ blockSums, int* __restrict__ blockOffsets, int nb) {
    __shared__ int sd[256];
    int tid = threadIdx.x;
    int v = (tid < nb) ? blockSums[tid] : 0;
    sd[tid] = v;
    __syncthreads();
    for (int off = 1; off < 256; off <<= 1) {
        int t = (tid >= off) ? sd[tid - off] : 0;
        __syncthreads();
        sd[tid] += t;
        __syncthreads();
    }
    if (tid < nb) blockOffsets[tid] = sd[tid] - v; // exclusive
}

// scanC: fine offsets + cursor init + dinv1/dinv2 (fused)
__global__ void scanC_kernel(const int* __restrict__ indeg, const int* __restrict__ blockOffsets,
                             int* __restrict__ offsets, int* __restrict__ cursor,
                             float* __restrict__ dinv1, float* __restrict__ dinv2,
                             int N, int E) {
    __shared__ int sd[256];
    int tid = threadIdx.x;
    int base = blockIdx.x * 1024 + tid * 4;
    int v[4], s = 0;
    #pragma unroll
    for (int j = 0; j < 4; ++j) { v[j] = (base + j < N) ? indeg[base + j] : 0; s += v[j]; }
    sd[tid] = s;
    __syncthreads();
    for (int off = 1; off < 256; off <<= 1) {
        int t = (tid >= off) ? sd[tid - off] : 0;
        __syncthreads();
        sd[tid] += t;
        __syncthreads();
    }
    int ex = blockOffsets[blockIdx.x] + sd[tid] - s;
    #pragma unroll
    for (int j = 0; j < 4; ++j) {
        if (base + j < N) {
            offsets[base + j] = ex;
            cursor[base + j] = ex;
            ex += v[j];
            int dg = v[j];
            dinv1[base + j] = rsqrtf((float)(dg + 1));
            dinv2[base + j] = (dg > 0) ? rsqrtf((float)dg) : 0.0f;
        }
    }
    if (blockIdx.x == 0 && tid == 0) offsets[N] = E;
}

// ---------------- pass 1: coarse scatter with LDS binning (dense writes) ----------------
__global__ __launch_bounds__(256) void coarse_scatter_kernel(const int* __restrict__ src,
                                                             const int* __restrict__ dst,
                                                             int* __restrict__ ccur,
                                                             int2* __restrict__ tmp, int E) {
    __shared__ int2 buf[EPB];                 // 16 KB
    __shared__ int cnt[NBKT], lofs[NBKT], gofs[NBKT];
    int base = blockIdx.x * EPB;
    int n = E - base; if (n > EPB) n = EPB;

    for (int i = threadIdx.x; i < NBKT; i += 256) cnt[i] = 0;
    __syncthreads();

    int2 v[8]; int bk[8], loc[8];
    #pragma unroll
    for (int j = 0; j < 8; ++j) {
        int o = threadIdx.x + j * 256;
        bk[j] = -1;
        if (o < n) {
            v[j].x = src[base + o];
            v[j].y = dst[base + o];
            bk[j]  = v[j].y >> BSH;
            loc[j] = atomicAdd(&cnt[bk[j]], 1);
        }
    }
    __syncthreads();
    if (threadIdx.x == 0) {
        int run = 0;
        for (int b = 0; b < NBKT; ++b) { lofs[b] = run; run += cnt[b]; }
    }
    __syncthreads();
    if (threadIdx.x < NBKT && cnt[threadIdx.x] > 0)
        gofs[threadIdx.x] = atomicAdd(&ccur[threadIdx.x], cnt[threadIdx.x]);
    __syncthreads();
    #pragma unroll
    for (int j = 0; j < 8; ++j)
        if (bk[j] >= 0) buf[lofs[bk[j]] + loc[j]] = v[j];
    __syncthreads();
    // dense run-out: consecutive i -> consecutive global addresses per bucket
    for (int i = threadIdx.x; i < n; i += 256) {
        int2 e = buf[i];
        int b = e.y >> BSH;
        tmp[gofs[b] + (i - lofs[b])] = e;
    }
}

// ---------------- pass 2: fine scatter within L2-resident bucket windows ----------------
__global__ __launch_bounds__(256) void fine_scatter_kernel(const int2* __restrict__ tmp,
                                                           int* __restrict__ cursor,
                                                           int* __restrict__ sorted_src, int E) {
    // bijective chunked XCD swizzle: consecutive tmp chunks (same bucket) -> same XCD
    int nwg = gridDim.x, bid = blockIdx.x;
    int q = nwg / 8, r = nwg % 8;
    int xcd = bid % 8, idx = bid / 8;
    int wg = (xcd < r ? xcd * (q + 1) : r * (q + 1) + (xcd - r) * q) + idx;
    int base = wg * 1024;
    #pragma unroll
    for (int j = 0; j < 4; ++j) {
        int i = base + threadIdx.x + j * 256;
        if (i < E) {
            int2 e = tmp[i];
            int p = atomicAdd(&cursor[e.y], 1);
            sorted_src[p] = e.x;
        }
    }
}

// ---------------- GEMM: Xs = (in_feat @ W1) * dinv1[node] ----------------
__global__ __launch_bounds__(256, 4) void gemm_kernel(const float* __restrict__ A,
                                                      const float* __restrict__ W,
                                                      const float* __restrict__ dinv1,
                                                      float* __restrict__ Xs, int N) {
    __shared__ float Ws[IN_F * H_F]; // 32 KB
    for (int i = threadIdx.x; i < IN_F * H_F / 4; i += 256)
        reinterpret_cast<float4*>(Ws)[i] = reinterpret_cast<const float4*>(W)[i];
    __syncthreads();

    int wid  = (blockIdx.x * blockDim.x + threadIdx.x) >> 6;
    int lane = threadIdx.x & 63;
    int n0   = wid * 4;
    if (n0 >= N) return;

    const float4* r0 = reinterpret_cast<const float4*>(A + (size_t)(n0 + 0) * IN_F);
    const float4* r1 = reinterpret_cast<const float4*>(A + (size_t)(n0 + 1) * IN_F);
    const float4* r2 = reinterpret_cast<const float4*>(A + (size_t)(n0 + 2) * IN_F);
    const float4* r3 = reinterpret_cast<const float4*>(A + (size_t)(n0 + 3) * IN_F);
    float acc0 = 0.f, acc1 = 0.f, acc2 = 0.f, acc3 = 0.f;
    #pragma unroll 4
    for (int k4 = 0; k4 < IN_F / 4; ++k4) {
        float4 a0 = r0[k4], a1 = r1[k4], a2 = r2[k4], a3 = r3[k4];
        float w0 = Ws[(k4 * 4 + 0) * H_F + lane];
        float w1 = Ws[(k4 * 4 + 1) * H_F + lane];
        float w2 = Ws[(k4 * 4 + 2) * H_F + lane];
        float w3 = Ws[(k4 * 4 + 3) * H_F + lane];
        acc0 += a0.x * w0 + a0.y * w1 + a0.z * w2 + a0.w * w3;
        acc1 += a1.x * w0 + a1.y * w1 + a1.z * w2 + a1.w * w3;
        acc2 += a2.x * w0 + a2.y * w1 + a2.z * w2 + a2.w * w3;
        acc3 += a3.x * w0 + a3.y * w1 + a3.z * w2 + a3.w * w3;
    }
    Xs[(size_t)(n0 + 0) * H_F + lane] = acc0 * dinv1[n0 + 0];
    Xs[(size_t)(n0 + 1) * H_F + lane] = acc1 * dinv1[n0 + 1];
    Xs[(size_t)(n0 + 2) * H_F + lane] = acc2 * dinv1[n0 + 2];
    Xs[(size_t)(n0 + 3) * H_F + lane] = acc3 * dinv1[n0 + 3];
}

// ---------------- prop1 (gather): h1[d] = dinv1[d]*(sum Xs[s] + Xs[d]) ----------------
__global__ __launch_bounds__(256) void prop1_kernel(const int* __restrict__ offsets,
                                                    const int* __restrict__ sorted_src,
                                                    const float* __restrict__ Xs,
                                                    const float* __restrict__ dinv1,
                                                    float* __restrict__ h1, int N) {
    int gtid = blockIdx.x * blockDim.x + threadIdx.x;
    int wid  = gtid >> 6;
    int lane = threadIdx.x & 63;
    if (wid >= N) return;
    int d = wid;

    int beg = offsets[d], end = offsets[d + 1];
    float acc = 0.f;
    for (int i0 = beg; i0 < end; i0 += 64) {
        int cnt = end - i0; if (cnt > 64) cnt = 64;
        int s_l = 0;
        if (i0 + lane < end) s_l = sorted_src[i0 + lane];
        int j = 0;
        for (; j + 4 <= cnt; j += 4) {
            int s0 = __shfl(s_l, j + 0), s1 = __shfl(s_l, j + 1);
            int s2 = __shfl(s_l, j + 2), s3 = __shfl(s_l, j + 3);
            float x0 = Xs[(size_t)s0 * H_F + lane];
            float x1 = Xs[(size_t)s1 * H_F + lane];
            float x2 = Xs[(size_t)s2 * H_F + lane];
            float x3 = Xs[(size_t)s3 * H_F + lane];
            acc += x0; acc += x1; acc += x2; acc += x3;
        }
        for (; j < cnt; ++j) {
            int s = __shfl(s_l, j);
            acc += Xs[(size_t)s * H_F + lane];
        }
    }
    float dv = dinv1[d];
    h1[(size_t)d * H_F + lane] = dv * (acc + Xs[(size_t)d * H_F + lane]);
}

// ---------------- prop2 (gather) + alpha combine ----------------
__global__ __launch_bounds__(256) void prop2_kernel(const int* __restrict__ offsets,
                                                    const int* __restrict__ sorted_src,
                                                    const float* __restrict__ h1,
                                                    const float* __restrict__ dinv2,
                                                    const float* __restrict__ alphas,
                                                    float* __restrict__ out, int N) {
    int gtid = blockIdx.x * blockDim.x + threadIdx.x;
    int wid  = gtid >> 6;
    int lane = threadIdx.x & 63;
    if (wid >= N) return;
    int d = wid;

    float e0 = expf(alphas[0]), e1 = expf(alphas[1]);
    float a0 = e0 / (e0 + e1), a1 = e1 / (e0 + e1);

    int beg = offsets[d], end = offsets[d + 1];
    float acc = 0.f;
    for (int i0 = beg; i0 < end; i0 += 64) {
        int cnt = end - i0; if (cnt > 64) cnt = 64;
        int s_l = 0; float w_l = 0.f;
        if (i0 + lane < end) { s_l = sorted_src[i0 + lane]; w_l = dinv2[s_l]; }
        int j = 0;
        for (; j + 4 <= cnt; j += 4) {
            int   s0 = __shfl(s_l, j + 0), s1 = __shfl(s_l, j + 1);
            int   s2 = __shfl(s_l, j + 2), s3 = __shfl(s_l, j + 3);
            float w0 = __shfl(w_l, j + 0), w1 = __shfl(w_l, j + 1);
            float w2 = __shfl(w_l, j + 2), w3 = __shfl(w_l, j + 3);
            float x0 = h1[(size_t)s0 * H_F + lane];
            float x1 = h1[(size_t)s1 * H_F + lane];
            float x2 = h1[(size_t)s2 * H_F + lane];
            float x3 = h1[(size_t)s3 * H_F + lane];
            acc += x0 * w0; acc += x1 * w1; acc += x2 * w2; acc += x3 * w3;
        }
        for (; j < cnt; ++j) {
            int   s = __shfl(s_l, j);
            float w = __shfl(w_l, j);
            acc += h1[(size_t)s * H_F + lane] * w;
        }
    }
    out[(size_t)d * H_F + lane] = a0 * h1[(size_t)d * H_F + lane] + a1 * dinv2[d] * acc;
}

extern "C" void kernel_launch(void* const* d_in, const int* in_sizes, int n_in,
                              void* d_out, int out_size, void* d_ws, size_t ws_size,
                              hipStream_t stream) {
    const int*   edge_index = (const int*)d_in[0];   // [2, E]
    const float* in_feat    = (const float*)d_in[1]; // [N, 128]
    const float* W1         = (const float*)d_in[2]; // [128, 64]
    const float* alphas     = (const float*)d_in[3]; // [2]
    float*       out        = (float*)d_out;         // [N, 64]

    const int* src = edge_index;
    const int* dst = edge_index + N_EDGES;

    // workspace layout
    char* ws = (char*)d_ws;
    size_t featBytes = (size_t)N_NODES * H_F * sizeof(float); // 25.6 MB
    float* Xs     = (float*)(ws);                    // 25.6 MB
    int2*  tmp    = (int2*)(ws);                     // 12.8 MB — aliases Xs (dead until gemm)
    float* h1     = (float*)(ws + featBytes);        // 25.6 MB
    char*  p      = ws + 2 * featBytes;
    int*   sorted = (int*)p;          p += (size_t)N_EDGES * 4;       // 6.4 MB
    int*   offs   = (int*)p;          p += (size_t)(N_NODES + 1) * 4;
    int*   cursor = (int*)p;          p += (size_t)N_NODES * 4;
    int*   indeg  = (int*)p;          p += (size_t)N_NODES * 4;
    int*   ccnt   = (int*)p;          p += (size_t)NBKT * 4;          // contiguous with indeg
    int*   ccur   = (int*)p;          p += (size_t)NBKT * 4;
    float* dinv1  = (float*)p;        p += (size_t)N_NODES * 4;
    float* dinv2  = (float*)p;        p += (size_t)N_NODES * 4;
    int*   bsums  = (int*)p;          p += 256 * 4;
    int*   boffs  = (int*)p;

    const int NB = (N_NODES + 1023) / 1024; // 98 scan blocks

    hipMemsetAsync(indeg, 0, ((size_t)N_NODES + NBKT) * sizeof(int), stream); // indeg + ccnt

    hist_kernel<<<1024, 256, 0, stream>>>(dst, indeg, ccnt, N_EDGES);
    scan_coarse_kernel<<<1, 64, 0, stream>>>(ccnt, ccur);
    scanA_kernel<<<NB, 256, 0, stream>>>(indeg, bsums, N_NODES);
    scanB_kernel<<<1, 256, 0, stream>>>(bsums, boffs, NB);
    scanC_kernel<<<NB, 256, 0, stream>>>(indeg, boffs, offs, cursor, dinv1, dinv2,
                                         N_NODES, N_EDGES);

    coarse_scatter_kernel<<<(N_EDGES + EPB - 1) / EPB, 256, 0, stream>>>(src, dst, ccur, tmp, N_EDGES);
    fine_scatter_kernel<<<(N_EDGES + 1023) / 1024, 256, 0, stream>>>(tmp, cursor, sorted, N_EDGES);

    gemm_kernel<<<(N_NODES / 4 * 64) / 256, 256, 0, stream>>>(in_feat, W1, dinv1, Xs, N_NODES);

    int nblocks = (N_NODES * 64 + 255) / 256; // one wave per node
    prop1_kernel<<<nblocks, 256, 0, stream>>>(offs, sorted, Xs, dinv1, h1, N_NODES);
    prop2_kernel<<<nblocks, 256, 0, stream>>>(offs, sorted, h1, dinv2, alphas, out, N_NODES);
}

// Round 4
// 328.299 us; speedup vs baseline: 3.0071x; 1.2297x over previous
//
#include <hip/hip_runtime.h>

#define N_NODES 100000
#define N_EDGES 1600000
#define IN_F 128
#define H_F 64

#define NBKT 49   // coarse buckets: dst >> 11
#define BSH 11
#define EPB 2048  // edges per block in coarse scatter

// ---- bf16 helpers (round-to-nearest-even) ----
static __device__ __forceinline__ unsigned short f2bf(float f) {
    unsigned int u = __float_as_uint(f);
    unsigned int r = (u + 0x7FFFu + ((u >> 16) & 1u)) >> 16;
    return (unsigned short)r;
}
static __device__ __forceinline__ float bf2f(unsigned short v) {
    return __uint_as_float(((unsigned int)v) << 16);
}
static __device__ __forceinline__ unsigned int pk2(float a, float b) {
    return (unsigned int)f2bf(a) | ((unsigned int)f2bf(b) << 16);
}

// ---------------- degree + coarse histogram (fused) ----------------
__global__ __launch_bounds__(256) void hist_kernel(const int* __restrict__ dst,
                                                   int* __restrict__ indeg,
                                                   int* __restrict__ ccnt, int E) {
    __shared__ int lh[NBKT];
    for (int i = threadIdx.x; i < NBKT; i += 256) lh[i] = 0;
    __syncthreads();
    int stride = gridDim.x * blockDim.x;
    for (int i = blockIdx.x * blockDim.x + threadIdx.x; i < E; i += stride) {
        int d = dst[i];
        atomicAdd(&indeg[d], 1);
        atomicAdd(&lh[d >> BSH], 1);
    }
    __syncthreads();
    for (int i = threadIdx.x; i < NBKT; i += 256)
        if (lh[i]) atomicAdd(&ccnt[i], lh[i]);
}

__global__ void scan_coarse_kernel(const int* __restrict__ ccnt,
                                   int* __restrict__ ccur) {
    if (threadIdx.x == 0) {
        int run = 0;
        for (int b = 0; b < NBKT; ++b) { ccur[b] = run; run += ccnt[b]; }
    }
}

// ---------------- exclusive scan of indeg (1024 elems / block) ----------------
__global__ void scanA_kernel(const int* __restrict__ indeg, int* __restrict__ blockSums, int N) {
    __shared__ int sd[256];
    int tid = threadIdx.x;
    int base = blockIdx.x * 1024 + tid * 4;
    int s = 0;
    #pragma unroll
    for (int j = 0; j < 4; ++j) s += (base + j < N) ? indeg[base + j] : 0;
    sd[tid] = s;
    __syncthreads();
    for (int off = 128; off > 0; off >>= 1) {
        if (tid < off) sd[tid] += sd[tid + off];
        __syncthreads();
    }
    if (tid == 0) blockSums[blockIdx.x] = sd[0];
}

__global__ void scanB_kernel(const int* __restrict__ blockSums, int* __restrict__ blockOffsets, int nb) {
    __shared__ int sd[256];
    int tid = threadIdx.x;
    int v = (tid < nb) ? blockSums[tid] : 0;
    sd[tid] = v;
    __syncthreads();
    for (int off = 1; off < 256; off <<= 1) {
        int t = (tid >= off) ? sd[tid - off] : 0;
        __syncthreads();
        sd[tid] += t;
        __syncthreads();
    }
    if (tid < nb) blockOffsets[tid] = sd[tid] - v; // exclusive
}

// scanC: fine offsets + cursor init + dinv1/dinv2 (fused)
__global__ void scanC_kernel(const int* __restrict__ indeg, const int* __restrict__ blockOffsets,
                             int* __restrict__ offsets, int* __restrict__ cursor,
                             float* __restrict__ dinv1, float* __restrict__ dinv2,
                             int N, int E) {
    __shared__ int sd[256];
    int tid = threadIdx.x;
    int base = blockIdx.x * 1024 + tid * 4;
    int v[4], s = 0;
    #pragma unroll
    for (int j = 0; j < 4; ++j) { v[j] = (base + j < N) ? indeg[base + j] : 0; s += v[j]; }
    sd[tid] = s;
    __syncthreads();
    for (int off = 1; off < 256; off <<= 1) {
        int t = (tid >= off) ? sd[tid - off] : 0;
        __syncthreads();
        sd[tid] += t;
        __syncthreads();
    }
    int ex = blockOffsets[blockIdx.x] + sd[tid] - s;
    #pragma unroll
    for (int j = 0; j < 4; ++j) {
        if (base + j < N) {
            offsets[base + j] = ex;
            cursor[base + j] = ex;
            ex += v[j];
            int dg = v[j];
            dinv1[base + j] = rsqrtf((float)(dg + 1));
            dinv2[base + j] = (dg > 0) ? rsqrtf((float)dg) : 0.0f;
        }
    }
    if (blockIdx.x == 0 && tid == 0) offsets[N] = E;
}

// ---------------- pass 1: coarse scatter with LDS binning (dense writes) ----------------
__global__ __launch_bounds__(256) void coarse_scatter_kernel(const int* __restrict__ src,
                                                             const int* __restrict__ dst,
                                                             int* __restrict__ ccur,
                                                             int2* __restrict__ tmp, int E) {
    __shared__ int2 buf[EPB];                 // 16 KB
    __shared__ int cnt[NBKT], lofs[NBKT], gofs[NBKT];
    int base = blockIdx.x * EPB;
    int n = E - base; if (n > EPB) n = EPB;

    for (int i = threadIdx.x; i < NBKT; i += 256) cnt[i] = 0;
    __syncthreads();

    int2 v[8]; int bk[8], loc[8];
    #pragma unroll
    for (int j = 0; j < 8; ++j) {
        int o = threadIdx.x + j * 256;
        bk[j] = -1;
        if (o < n) {
            v[j].x = src[base + o];
            v[j].y = dst[base + o];
            bk[j]  = v[j].y >> BSH;
            loc[j] = atomicAdd(&cnt[bk[j]], 1);
        }
    }
    __syncthreads();
    if (threadIdx.x == 0) {
        int run = 0;
        for (int b = 0; b < NBKT; ++b) { lofs[b] = run; run += cnt[b]; }
    }
    __syncthreads();
    if (threadIdx.x < NBKT && cnt[threadIdx.x] > 0)
        gofs[threadIdx.x] = atomicAdd(&ccur[threadIdx.x], cnt[threadIdx.x]);
    __syncthreads();
    #pragma unroll
    for (int j = 0; j < 8; ++j)
        if (bk[j] >= 0) buf[lofs[bk[j]] + loc[j]] = v[j];
    __syncthreads();
    for (int i = threadIdx.x; i < n; i += 256) {
        int2 e = buf[i];
        int b = e.y >> BSH;
        tmp[gofs[b] + (i - lofs[b])] = e;
    }
}

// ---------------- pass 2: fine scatter within L2-resident bucket windows ----------------
__global__ __launch_bounds__(256) void fine_scatter_kernel(const int2* __restrict__ tmp,
                                                           int* __restrict__ cursor,
                                                           int* __restrict__ sorted_src, int E) {
    int nwg = gridDim.x, bid = blockIdx.x;
    int q = nwg / 8, r = nwg % 8;
    int xcd = bid % 8, idx = bid / 8;
    int wg = (xcd < r ? xcd * (q + 1) : r * (q + 1) + (xcd - r) * q) + idx;
    int base = wg * 1024;
    #pragma unroll
    for (int j = 0; j < 4; ++j) {
        int i = base + threadIdx.x + j * 256;
        if (i < E) {
            int2 e = tmp[i];
            int p = atomicAdd(&cursor[e.y], 1);
            sorted_src[p] = e.x;
        }
    }
}

// ---------------- GEMM: Xs_bf = bf16((in_feat @ W1) * dinv1[node]) ----------------
// lane = node (64 nodes/wave). Per-lane coalesced-in-time row loads (no redundancy),
// W read via wave-uniform ds_read_b128 (free LDS broadcast). acc[64 feats] in regs.
__global__ __launch_bounds__(256) void gemm_kernel(const float* __restrict__ A,
                                                   const float* __restrict__ W,
                                                   const float* __restrict__ dinv1,
                                                   unsigned short* __restrict__ Xs, int N) {
    __shared__ float Ws[IN_F * H_F]; // 32 KB, k-major [128][64]
    for (int i = threadIdx.x; i < IN_F * H_F / 4; i += 256)
        reinterpret_cast<float4*>(Ws)[i] = reinterpret_cast<const float4*>(W)[i];
    __syncthreads();
    const float4* W4 = reinterpret_cast<const float4*>(Ws);

    int wid  = blockIdx.x * 4 + (threadIdx.x >> 6);
    int lane = threadIdx.x & 63;
    int node = wid * 64 + lane;
    int nd   = node < N ? node : N - 1;
    const float4* rowp = reinterpret_cast<const float4*>(A + (size_t)nd * IN_F);

    float4 acc[16];
    #pragma unroll
    for (int f4 = 0; f4 < 16; ++f4) acc[f4] = make_float4(0.f, 0.f, 0.f, 0.f);

    float4 a[8], nbuf[8];
    #pragma unroll
    for (int j = 0; j < 8; ++j) nbuf[j] = rowp[j];

    #pragma unroll 1
    for (int c = 0; c < 4; ++c) {       // K chunks of 32
        #pragma unroll
        for (int j = 0; j < 8; ++j) a[j] = nbuf[j];
        if (c < 3) {
            #pragma unroll
            for (int j = 0; j < 8; ++j) nbuf[j] = rowp[(c + 1) * 8 + j];
        }
        const float4* wc = W4 + c * 32 * (H_F / 4);
        #pragma unroll
        for (int k4 = 0; k4 < 8; ++k4) {
            #pragma unroll
            for (int kk = 0; kk < 4; ++kk) {
                float av = (kk == 0) ? a[k4].x : (kk == 1) ? a[k4].y
                         : (kk == 2) ? a[k4].z : a[k4].w;
                const float4* wrow = wc + (k4 * 4 + kk) * (H_F / 4);
                #pragma unroll
                for (int f4 = 0; f4 < 16; ++f4) {
                    float4 w = wrow[f4];   // uniform ds_read_b128 (broadcast)
                    acc[f4].x += av * w.x;
                    acc[f4].y += av * w.y;
                    acc[f4].z += av * w.z;
                    acc[f4].w += av * w.w;
                }
            }
        }
    }

    if (node < N) {
        float dv = dinv1[node];
        uint4* orow = reinterpret_cast<uint4*>(Xs + (size_t)node * H_F);
        #pragma unroll
        for (int m = 0; m < 8; ++m) {
            float4 p = acc[2 * m], q = acc[2 * m + 1];
            uint4 t;
            t.x = pk2(p.x * dv, p.y * dv);
            t.y = pk2(p.z * dv, p.w * dv);
            t.z = pk2(q.x * dv, q.y * dv);
            t.w = pk2(q.z * dv, q.w * dv);
            orow[m] = t;
        }
    }
}

// ---------------- prop1 (gather, bf16 table): ----------------
// h1[d] = dinv1[d]*(sum Xs[s] + Xs[d]);  h1s[d] = h1[d]*dinv2[d]
__global__ __launch_bounds__(256) void prop1_kernel(const int* __restrict__ offsets,
                                                    const int* __restrict__ sorted_src,
                                                    const unsigned short* __restrict__ Xs,
                                                    const float* __restrict__ dinv1,
                                                    const float* __restrict__ dinv2,
                                                    unsigned short* __restrict__ h1,
                                                    unsigned short* __restrict__ h1s, int N) {
    int wid  = (blockIdx.x * blockDim.x + threadIdx.x) >> 6;
    int lane = threadIdx.x & 63;
    if (wid >= N) return;
    int d = wid;

    int beg = offsets[d], end = offsets[d + 1];
    float acc = 0.f;
    for (int i0 = beg; i0 < end; i0 += 64) {
        int cnt = end - i0; if (cnt > 64) cnt = 64;
        int s_l = 0;
        if (i0 + lane < end) s_l = sorted_src[i0 + lane];
        int j = 0;
        for (; j + 4 <= cnt; j += 4) {
            int s0 = __shfl(s_l, j + 0), s1 = __shfl(s_l, j + 1);
            int s2 = __shfl(s_l, j + 2), s3 = __shfl(s_l, j + 3);
            float x0 = bf2f(Xs[(size_t)s0 * H_F + lane]);
            float x1 = bf2f(Xs[(size_t)s1 * H_F + lane]);
            float x2 = bf2f(Xs[(size_t)s2 * H_F + lane]);
            float x3 = bf2f(Xs[(size_t)s3 * H_F + lane]);
            acc += x0; acc += x1; acc += x2; acc += x3;
        }
        for (; j < cnt; ++j) {
            int s = __shfl(s_l, j);
            acc += bf2f(Xs[(size_t)s * H_F + lane]);
        }
    }
    float dv = dinv1[d];
    float h  = dv * (acc + bf2f(Xs[(size_t)d * H_F + lane]));
    h1 [(size_t)d * H_F + lane] = f2bf(h);
    h1s[(size_t)d * H_F + lane] = f2bf(h * dinv2[d]);
}

// ---------------- prop2 (gather, bf16 h1s table) + alpha combine ----------------
// out[d] = a0*h1[d] + a1*dinv2[d]*sum(h1s[s])
__global__ __launch_bounds__(256) void prop2_kernel(const int* __restrict__ offsets,
                                                    const int* __restrict__ sorted_src,
                                                    const unsigned short* __restrict__ h1,
                                                    const unsigned short* __restrict__ h1s,
                                                    const float* __restrict__ dinv2,
                                                    const float* __restrict__ alphas,
                                                    float* __restrict__ out, int N) {
    int wid  = (blockIdx.x * blockDim.x + threadIdx.x) >> 6;
    int lane = threadIdx.x & 63;
    if (wid >= N) return;
    int d = wid;

    float e0 = expf(alphas[0]), e1 = expf(alphas[1]);
    float a0 = e0 / (e0 + e1), a1 = e1 / (e0 + e1);

    int beg = offsets[d], end = offsets[d + 1];
    float acc = 0.f;
    for (int i0 = beg; i0 < end; i0 += 64) {
        int cnt = end - i0; if (cnt > 64) cnt = 64;
        int s_l = 0;
        if (i0 + lane < end) s_l = sorted_src[i0 + lane];
        int j = 0;
        for (; j + 4 <= cnt; j += 4) {
            int s0 = __shfl(s_l, j + 0), s1 = __shfl(s_l, j + 1);
            int s2 = __shfl(s_l, j + 2), s3 = __shfl(s_l, j + 3);
            float x0 = bf2f(h1s[(size_t)s0 * H_F + lane]);
            float x1 = bf2f(h1s[(size_t)s1 * H_F + lane]);
            float x2 = bf2f(h1s[(size_t)s2 * H_F + lane]);
            float x3 = bf2f(h1s[(size_t)s3 * H_F + lane]);
            acc += x0; acc += x1; acc += x2; acc += x3;
        }
        for (; j < cnt; ++j) {
            int s = __shfl(s_l, j);
            acc += bf2f(h1s[(size_t)s * H_F + lane]);
        }
    }
    out[(size_t)d * H_F + lane] = a0 * bf2f(h1[(size_t)d * H_F + lane]) + a1 * dinv2[d] * acc;
}

extern "C" void kernel_launch(void* const* d_in, const int* in_sizes, int n_in,
                              void* d_out, int out_size, void* d_ws, size_t ws_size,
                              hipStream_t stream) {
    const int*   edge_index = (const int*)d_in[0];   // [2, E]
    const float* in_feat    = (const float*)d_in[1]; // [N, 128]
    const float* W1         = (const float*)d_in[2]; // [128, 64]
    const float* alphas     = (const float*)d_in[3]; // [2]
    float*       out        = (float*)d_out;         // [N, 64]

    const int* src = edge_index;
    const int* dst = edge_index + N_EDGES;

    // workspace layout (bf16 tables: N*64*2 = 12.8 MB each)
    char* ws = (char*)d_ws;
    size_t tabBytes = (size_t)N_NODES * H_F * 2;
    unsigned short* Xs  = (unsigned short*)(ws);                 // 12.8 MB
    int2*           tmp = (int2*)(ws);                           // 12.8 MB — aliases Xs (dead until gemm)
    unsigned short* h1  = (unsigned short*)(ws + tabBytes);      // 12.8 MB
    unsigned short* h1s = (unsigned short*)(ws + 2 * tabBytes);  // 12.8 MB
    char* p = ws + 3 * tabBytes;
    int*   sorted = (int*)p;   p += (size_t)N_EDGES * 4;         // 6.4 MB
    int*   offs   = (int*)p;   p += (size_t)(N_NODES + 4) * 4;
    int*   cursor = (int*)p;   p += (size_t)N_NODES * 4;
    int*   indeg  = (int*)p;   p += (size_t)N_NODES * 4;
    int*   ccnt   = (int*)p;   p += (size_t)NBKT * 4;            // contiguous with indeg (one memset)
    int*   ccur   = (int*)p;   p += (size_t)NBKT * 4;
    float* dinv1  = (float*)p; p += (size_t)N_NODES * 4;
    float* dinv2  = (float*)p; p += (size_t)N_NODES * 4;
    int*   bsums  = (int*)p;   p += 256 * 4;
    int*   boffs  = (int*)p;

    const int NB = (N_NODES + 1023) / 1024; // 98 scan blocks

    hipMemsetAsync(indeg, 0, ((size_t)N_NODES + NBKT) * sizeof(int), stream); // indeg + ccnt

    hist_kernel<<<1024, 256, 0, stream>>>(dst, indeg, ccnt, N_EDGES);
    scan_coarse_kernel<<<1, 64, 0, stream>>>(ccnt, ccur);
    scanA_kernel<<<NB, 256, 0, stream>>>(indeg, bsums, N_NODES);
    scanB_kernel<<<1, 256, 0, stream>>>(bsums, boffs, NB);
    scanC_kernel<<<NB, 256, 0, stream>>>(indeg, boffs, offs, cursor, dinv1, dinv2,
                                         N_NODES, N_EDGES);

    coarse_scatter_kernel<<<(N_EDGES + EPB - 1) / EPB, 256, 0, stream>>>(src, dst, ccur, tmp, N_EDGES);
    fine_scatter_kernel<<<(N_EDGES + 1023) / 1024, 256, 0, stream>>>(tmp, cursor, sorted, N_EDGES);

    // gemm must run after fine_scatter (tmp aliases Xs)
    int gemm_waves  = (N_NODES + 63) / 64;            // 1563
    int gemm_blocks = (gemm_waves + 3) / 4;           // 391
    gemm_kernel<<<gemm_blocks, 256, 0, stream>>>(in_feat, W1, dinv1, Xs, N_NODES);

    int nblocks = (N_NODES * 64 + 255) / 256; // one wave per node
    prop1_kernel<<<nblocks, 256, 0, stream>>>(offs, sorted, Xs, dinv1, dinv2, h1, h1s, N_NODES);
    prop2_kernel<<<nblocks, 256, 0, stream>>>(offs, sorted, h1, h1s, dinv2, alphas, out, N_NODES);
}

// Round 5
// 239.459 us; speedup vs baseline: 4.1228x; 1.3710x over previous
//
#include <hip/hip_runtime.h>

#define N_NODES 100000
#define N_EDGES 1600000
#define IN_F 128
#define H_F 64

#define BSH 10          // coarse bucket = dst >> 10
#define BNODES 1024     // nodes per bucket
#define NBKT 98         // ceil(100000 / 1024)
#define EPB 4096        // edges per block in coarse scatter

// ---- bf16 helpers (round-to-nearest-even) ----
static __device__ __forceinline__ unsigned short f2bf(float f) {
    unsigned int u = __float_as_uint(f);
    unsigned int r = (u + 0x7FFFu + ((u >> 16) & 1u)) >> 16;
    return (unsigned short)r;
}
static __device__ __forceinline__ float bf2f(unsigned short v) {
    return __uint_as_float(((unsigned int)v) << 16);
}
static __device__ __forceinline__ unsigned int pk2(float a, float b) {
    return (unsigned int)f2bf(a) | ((unsigned int)f2bf(b) << 16);
}

// ---------------- coarse histogram only (no per-node atomics) ----------------
__global__ __launch_bounds__(256) void hist_kernel(const int* __restrict__ dst,
                                                   int* __restrict__ ccnt, int E) {
    __shared__ int lh[4 * NBKT];   // per-wave sub-histograms
    int w = threadIdx.x >> 6;
    for (int i = threadIdx.x; i < 4 * NBKT; i += 256) lh[i] = 0;
    __syncthreads();
    int stride = gridDim.x * blockDim.x;
    for (int i = blockIdx.x * blockDim.x + threadIdx.x; i < E; i += stride)
        atomicAdd(&lh[w * NBKT + (dst[i] >> BSH)], 1);
    __syncthreads();
    for (int b = threadIdx.x; b < NBKT; b += 256) {
        int s = lh[b] + lh[NBKT + b] + lh[2 * NBKT + b] + lh[3 * NBKT + b];
        if (s) atomicAdd(&ccnt[b], s);
    }
}

// ---------------- coarse offsets (98 entries) + sentinel ----------------
__global__ void scan_coarse_kernel(const int* __restrict__ ccnt,
                                   int* __restrict__ cofs, int* __restrict__ ccur,
                                   int* __restrict__ offsets, int E) {
    if (threadIdx.x == 0) {
        int run = 0;
        for (int b = 0; b < NBKT; ++b) { cofs[b] = run; ccur[b] = run; run += ccnt[b]; }
        cofs[NBKT] = run;              // == E
        offsets[N_NODES] = E;          // sentinel for prop kernels
    }
}

// ---------------- pass 1: coarse scatter, packed (local_dst<<17 | src) ----------------
__global__ __launch_bounds__(256) void coarse_scatter_kernel(const int* __restrict__ src,
                                                             const int* __restrict__ dst,
                                                             int* __restrict__ ccur,
                                                             unsigned int* __restrict__ tmp, int E) {
    __shared__ unsigned int buf[EPB];               // 16 KB
    __shared__ int cnt[NBKT], lofs[NBKT], gofs[NBKT];
    int base = blockIdx.x * EPB;
    int n = E - base; if (n > EPB) n = EPB;

    for (int i = threadIdx.x; i < NBKT; i += 256) cnt[i] = 0;
    __syncthreads();

    unsigned int v[16]; int bk[16], loc[16];
    #pragma unroll
    for (int j = 0; j < 16; ++j) {
        int o = threadIdx.x + j * 256;
        bk[j] = -1;
        if (o < n) {
            int s = src[base + o];
            int d = dst[base + o];
            bk[j]  = d >> BSH;
            v[j]   = ((unsigned int)(d & (BNODES - 1)) << 17) | (unsigned int)s;
            loc[j] = atomicAdd(&cnt[bk[j]], 1);
        }
    }
    __syncthreads();
    if (threadIdx.x == 0) {
        int run = 0;
        for (int b = 0; b < NBKT; ++b) { lofs[b] = run; run += cnt[b]; }
    }
    __syncthreads();
    if (threadIdx.x < NBKT && cnt[threadIdx.x] > 0)
        gofs[threadIdx.x] = atomicAdd(&ccur[threadIdx.x], cnt[threadIdx.x]);
    __syncthreads();
    #pragma unroll
    for (int j = 0; j < 16; ++j)
        if (bk[j] >= 0) buf[lofs[bk[j]] + loc[j]] = v[j];
    __syncthreads();
    // dense run-out: consecutive i -> consecutive global addresses per bucket
    for (int i = threadIdx.x; i < n; i += 256) {
        unsigned int e = buf[i];
        int b = (int)(e >> 17) >> (BSH - 10); // local_dst -> but bucket needs full dst; recompute:
        // local_dst alone can't give bucket; recover via lofs search is wrong — instead
        // bucket is implied by position: find b s.t. lofs[b] <= i < lofs[b]+cnt[b].
        // Cheaper: store bucket in high bits? 27 bits used, 5 free -> not enough for 98.
        // Use binary search over lofs (98 entries, LDS, log2=7 steps).
        int lo = 0, hi = NBKT - 1;
        while (lo < hi) { int mid = (lo + hi + 1) >> 1; if (lofs[mid] <= i) lo = mid; else hi = mid - 1; }
        tmp[gofs[lo] + (i - lofs[lo])] = e;
    }
}

// ---------------- pass 2: per-bucket LDS pipeline ----------------
// one block per coarse bucket: histogram -> scan -> offsets/dinv -> fine scatter.
__global__ __launch_bounds__(512) void bucket_kernel(const unsigned int* __restrict__ tmp,
                                                     const int* __restrict__ cofs,
                                                     int* __restrict__ offsets,
                                                     int* __restrict__ sorted_src,
                                                     float* __restrict__ dinv1,
                                                     float* __restrict__ dinv2, int N) {
    __shared__ int cnt[BNODES];   // histogram, then reused as absolute cursor
    __shared__ int sd[512];
    int b   = blockIdx.x;
    int tid = threadIdx.x;
    int beg = cofs[b], end = cofs[b + 1];

    for (int i = tid; i < BNODES; i += 512) cnt[i] = 0;
    __syncthreads();
    for (int i = beg + tid; i < end; i += 512)
        atomicAdd(&cnt[tmp[i] >> 17], 1);
    __syncthreads();

    // exclusive scan of cnt[1024]: each thread owns 2 consecutive counters
    int c0 = cnt[2 * tid], c1 = cnt[2 * tid + 1];
    int s  = c0 + c1;
    sd[tid] = s;
    __syncthreads();
    for (int off = 1; off < 512; off <<= 1) {
        int t = (tid >= off) ? sd[tid - off] : 0;
        __syncthreads();
        sd[tid] += t;
        __syncthreads();
    }
    int ex = sd[tid] - s;                 // exclusive within bucket
    int g0 = beg + ex, g1 = beg + ex + c0;

    int node0 = b * BNODES + 2 * tid;
    if (node0 < N) {
        offsets[node0] = g0;
        dinv1[node0] = rsqrtf((float)(c0 + 1));
        dinv2[node0] = c0 ? rsqrtf((float)c0) : 0.0f;
    }
    if (node0 + 1 < N) {
        offsets[node0 + 1] = g1;
        dinv1[node0 + 1] = rsqrtf((float)(c1 + 1));
        dinv2[node0 + 1] = c1 ? rsqrtf((float)c1) : 0.0f;
    }
    __syncthreads();                      // done reading cnt as histogram
    cnt[2 * tid] = g0;                    // absolute cursors
    cnt[2 * tid + 1] = g1;
    __syncthreads();

    for (int i = beg + tid; i < end; i += 512) {
        unsigned int v = tmp[i];
        int p = atomicAdd(&cnt[v >> 17], 1);
        sorted_src[p] = (int)(v & 0x1FFFFu);
    }
}

// ---------------- GEMM: Xs_bf = bf16((in_feat @ W1) * dinv1[node]) ----------------
__global__ __launch_bounds__(256) void gemm_kernel(const float* __restrict__ A,
                                                   const float* __restrict__ W,
                                                   const float* __restrict__ dinv1,
                                                   unsigned short* __restrict__ Xs, int N) {
    __shared__ float Ws[IN_F * H_F]; // 32 KB, k-major [128][64]
    for (int i = threadIdx.x; i < IN_F * H_F / 4; i += 256)
        reinterpret_cast<float4*>(Ws)[i] = reinterpret_cast<const float4*>(W)[i];
    __syncthreads();
    const float4* W4 = reinterpret_cast<const float4*>(Ws);

    int wid  = blockIdx.x * 4 + (threadIdx.x >> 6);
    int lane = threadIdx.x & 63;
    int node = wid * 64 + lane;
    int nd   = node < N ? node : N - 1;
    const float4* rowp = reinterpret_cast<const float4*>(A + (size_t)nd * IN_F);

    float4 acc[16];
    #pragma unroll
    for (int f4 = 0; f4 < 16; ++f4) acc[f4] = make_float4(0.f, 0.f, 0.f, 0.f);

    float4 a[8], nbuf[8];
    #pragma unroll
    for (int j = 0; j < 8; ++j) nbuf[j] = rowp[j];

    #pragma unroll 1
    for (int c = 0; c < 4; ++c) {       // K chunks of 32
        #pragma unroll
        for (int j = 0; j < 8; ++j) a[j] = nbuf[j];
        if (c < 3) {
            #pragma unroll
            for (int j = 0; j < 8; ++j) nbuf[j] = rowp[(c + 1) * 8 + j];
        }
        const float4* wc = W4 + c * 32 * (H_F / 4);
        #pragma unroll
        for (int k4 = 0; k4 < 8; ++k4) {
            #pragma unroll
            for (int kk = 0; kk < 4; ++kk) {
                float av = (kk == 0) ? a[k4].x : (kk == 1) ? a[k4].y
                         : (kk == 2) ? a[k4].z : a[k4].w;
                const float4* wrow = wc + (k4 * 4 + kk) * (H_F / 4);
                #pragma unroll
                for (int f4 = 0; f4 < 16; ++f4) {
                    float4 w = wrow[f4];   // uniform ds_read_b128 (broadcast)
                    acc[f4].x += av * w.x;
                    acc[f4].y += av * w.y;
                    acc[f4].z += av * w.z;
                    acc[f4].w += av * w.w;
                }
            }
        }
    }

    if (node < N) {
        float dv = dinv1[node];
        uint4* orow = reinterpret_cast<uint4*>(Xs + (size_t)node * H_F);
        #pragma unroll
        for (int m = 0; m < 8; ++m) {
            float4 p = acc[2 * m], q = acc[2 * m + 1];
            uint4 t;
            t.x = pk2(p.x * dv, p.y * dv);
            t.y = pk2(p.z * dv, p.w * dv);
            t.z = pk2(q.x * dv, q.y * dv);
            t.w = pk2(q.z * dv, q.w * dv);
            orow[m] = t;
        }
    }
}

// ---------------- prop1 (gather, bf16 table) ----------------
// h1[d] = dinv1[d]*(sum Xs[s] + Xs[d]);  h1s[d] = h1[d]*dinv2[d]
__global__ __launch_bounds__(256) void prop1_kernel(const int* __restrict__ offsets,
                                                    const int* __restrict__ sorted_src,
                                                    const unsigned short* __restrict__ Xs,
                                                    const float* __restrict__ dinv1,
                                                    const float* __restrict__ dinv2,
                                                    unsigned short* __restrict__ h1,
                                                    unsigned short* __restrict__ h1s, int N) {
    int wid  = (blockIdx.x * blockDim.x + threadIdx.x) >> 6;
    int lane = threadIdx.x & 63;
    if (wid >= N) return;
    int d = wid;

    int beg = offsets[d], end = offsets[d + 1];
    float acc = 0.f;
    for (int i0 = beg; i0 < end; i0 += 64) {
        int cnt = end - i0; if (cnt > 64) cnt = 64;
        int s_l = 0;
        if (i0 + lane < end) s_l = sorted_src[i0 + lane];
        int j = 0;
        for (; j + 4 <= cnt; j += 4) {
            int s0 = __shfl(s_l, j + 0), s1 = __shfl(s_l, j + 1);
            int s2 = __shfl(s_l, j + 2), s3 = __shfl(s_l, j + 3);
            float x0 = bf2f(Xs[(size_t)s0 * H_F + lane]);
            float x1 = bf2f(Xs[(size_t)s1 * H_F + lane]);
            float x2 = bf2f(Xs[(size_t)s2 * H_F + lane]);
            float x3 = bf2f(Xs[(size_t)s3 * H_F + lane]);
            acc += x0; acc += x1; acc += x2; acc += x3;
        }
        for (; j < cnt; ++j) {
            int s = __shfl(s_l, j);
            acc += bf2f(Xs[(size_t)s * H_F + lane]);
        }
    }
    float dv = dinv1[d];
    float h  = dv * (acc + bf2f(Xs[(size_t)d * H_F + lane]));
    h1 [(size_t)d * H_F + lane] = f2bf(h);
    h1s[(size_t)d * H_F + lane] = f2bf(h * dinv2[d]);
}

// ---------------- prop2 (gather, bf16 h1s table) + alpha combine ----------------
__global__ __launch_bounds__(256) void prop2_kernel(const int* __restrict__ offsets,
                                                    const int* __restrict__ sorted_src,
                                                    const unsigned short* __restrict__ h1,
                                                    const unsigned short* __restrict__ h1s,
                                                    const float* __restrict__ dinv2,
                                                    const float* __restrict__ alphas,
                                                    float* __restrict__ out, int N) {
    int wid  = (blockIdx.x * blockDim.x + threadIdx.x) >> 6;
    int lane = threadIdx.x & 63;
    if (wid >= N) return;
    int d = wid;

    float e0 = expf(alphas[0]), e1 = expf(alphas[1]);
    float a0 = e0 / (e0 + e1), a1 = e1 / (e0 + e1);

    int beg = offsets[d], end = offsets[d + 1];
    float acc = 0.f;
    for (int i0 = beg; i0 < end; i0 += 64) {
        int cnt = end - i0; if (cnt > 64) cnt = 64;
        int s_l = 0;
        if (i0 + lane < end) s_l = sorted_src[i0 + lane];
        int j = 0;
        for (; j + 4 <= cnt; j += 4) {
            int s0 = __shfl(s_l, j + 0), s1 = __shfl(s_l, j + 1);
            int s2 = __shfl(s_l, j + 2), s3 = __shfl(s_l, j + 3);
            float x0 = bf2f(h1s[(size_t)s0 * H_F + lane]);
            float x1 = bf2f(h1s[(size_t)s1 * H_F + lane]);
            float x2 = bf2f(h1s[(size_t)s2 * H_F + lane]);
            float x3 = bf2f(h1s[(size_t)s3 * H_F + lane]);
            acc += x0; acc += x1; acc += x2; acc += x3;
        }
        for (; j < cnt; ++j) {
            int s = __shfl(s_l, j);
            acc += bf2f(h1s[(size_t)s * H_F + lane]);
        }
    }
    out[(size_t)d * H_F + lane] = a0 * bf2f(h1[(size_t)d * H_F + lane]) + a1 * dinv2[d] * acc;
}

extern "C" void kernel_launch(void* const* d_in, const int* in_sizes, int n_in,
                              void* d_out, int out_size, void* d_ws, size_t ws_size,
                              hipStream_t stream) {
    const int*   edge_index = (const int*)d_in[0];   // [2, E]
    const float* in_feat    = (const float*)d_in[1]; // [N, 128]
    const float* W1         = (const float*)d_in[2]; // [128, 64]
    const float* alphas     = (const float*)d_in[3]; // [2]
    float*       out        = (float*)d_out;         // [N, 64]

    const int* src = edge_index;
    const int* dst = edge_index + N_EDGES;

    // workspace layout (bf16 tables: N*64*2 = 12.8 MB each)
    char* ws = (char*)d_ws;
    size_t tabBytes = (size_t)N_NODES * H_F * 2;
    unsigned short* Xs  = (unsigned short*)(ws);                 // 12.8 MB
    unsigned int*   tmp = (unsigned int*)(ws);                   // 6.4 MB — aliases Xs (dead until gemm)
    unsigned short* h1  = (unsigned short*)(ws + tabBytes);      // 12.8 MB
    unsigned short* h1s = (unsigned short*)(ws + 2 * tabBytes);  // 12.8 MB
    char* p = ws + 3 * tabBytes;
    int*   sorted = (int*)p;   p += (size_t)N_EDGES * 4;         // 6.4 MB
    int*   offs   = (int*)p;   p += (size_t)(N_NODES + 4) * 4;
    float* dinv1  = (float*)p; p += (size_t)N_NODES * 4;
    float* dinv2  = (float*)p; p += (size_t)N_NODES * 4;
    int*   ccnt   = (int*)p;   p += (size_t)NBKT * 4;
    int*   cofs   = (int*)p;   p += (size_t)(NBKT + 1) * 4;
    int*   ccur   = (int*)p;   p += (size_t)NBKT * 4;

    hipMemsetAsync(ccnt, 0, (size_t)NBKT * sizeof(int), stream);

    hist_kernel<<<512, 256, 0, stream>>>(dst, ccnt, N_EDGES);
    scan_coarse_kernel<<<1, 64, 0, stream>>>(ccnt, cofs, ccur, offs, N_EDGES);
    coarse_scatter_kernel<<<(N_EDGES + EPB - 1) / EPB, 256, 0, stream>>>(src, dst, ccur, tmp, N_EDGES);
    bucket_kernel<<<NBKT, 512, 0, stream>>>(tmp, cofs, offs, sorted, dinv1, dinv2, N_NODES);

    // gemm must run after bucket_kernel (tmp aliases Xs)
    int gemm_waves  = (N_NODES + 63) / 64;            // 1563
    int gemm_blocks = (gemm_waves + 3) / 4;           // 391
    gemm_kernel<<<gemm_blocks, 256, 0, stream>>>(in_feat, W1, dinv1, Xs, N_NODES);

    int nblocks = (N_NODES * 64 + 255) / 256; // one wave per node
    prop1_kernel<<<nblocks, 256, 0, stream>>>(offs, sorted, Xs, dinv1, dinv2, h1, h1s, N_NODES);
    prop2_kernel<<<nblocks, 256, 0, stream>>>(offs, sorted, h1, h1s, dinv2, alphas, out, N_NODES);
}

// Round 6
// 194.875 us; speedup vs baseline: 5.0660x; 1.2288x over previous
//
#include <hip/hip_runtime.h>

#define N_NODES 100000
#define N_EDGES 1600000
#define IN_F 128
#define H_F 64

#define BSH 10          // coarse bucket = dst >> 10
#define BNODES 1024     // nodes per bucket
#define NBKT 98         // ceil(100000 / 1024)
#define EPB 4096        // edges per block in coarse scatter

typedef short short8 __attribute__((ext_vector_type(8)));
typedef float floatx4 __attribute__((ext_vector_type(4)));

union U16x8 { short8 v; unsigned short us[8]; unsigned int u[4]; };

// ---- bf16 helpers (round-to-nearest-even) ----
static __device__ __forceinline__ unsigned short f2bf(float f) {
    unsigned int u = __float_as_uint(f);
    unsigned int r = (u + 0x7FFFu + ((u >> 16) & 1u)) >> 16;
    return (unsigned short)r;
}
static __device__ __forceinline__ float bf2f(unsigned short v) {
    return __uint_as_float(((unsigned int)v) << 16);
}
static __device__ __forceinline__ unsigned int pk2(float a, float b) {
    return (unsigned int)f2bf(a) | ((unsigned int)f2bf(b) << 16);
}

// ---------------- W fragment pre-pack: wfrag[(ct*4+kc)*64 + lane] = uint4 ----------------
// A-operand frag for mfma_f32_16x16x32_bf16 computing D = W^T A^T:
// lane supplies W^T[f = ct*16 + (lane&15)][k = kc*32 + (lane>>4)*8 + 2r + h]
__global__ __launch_bounds__(256) void wpack_kernel(const float* __restrict__ W,
                                                    unsigned int* __restrict__ wfrag) {
    int i = blockIdx.x * 256 + threadIdx.x;   // [0, 8192)
    int reg = i & 3, lane = (i >> 2) & 63, fkc = i >> 8;
    int ct = fkc >> 2, kc = fkc & 3;
    int fcol = ct * 16 + (lane & 15);
    int k = kc * 32 + (lane >> 4) * 8 + reg * 2;
    wfrag[i] = pk2(W[k * 64 + fcol], W[(k + 1) * 64 + fcol]);
}

// ---------------- coarse histogram (98 bins, per-wave sub-histograms) ----------------
__global__ __launch_bounds__(256) void hist_kernel(const int* __restrict__ dst,
                                                   int* __restrict__ ccnt, int E) {
    __shared__ int lh[4 * NBKT];
    int w = threadIdx.x >> 6;
    for (int i = threadIdx.x; i < 4 * NBKT; i += 256) lh[i] = 0;
    __syncthreads();
    int stride = gridDim.x * blockDim.x;
    for (int i = blockIdx.x * blockDim.x + threadIdx.x; i < E; i += stride)
        atomicAdd(&lh[w * NBKT + (dst[i] >> BSH)], 1);
    __syncthreads();
    for (int b = threadIdx.x; b < NBKT; b += 256) {
        int s = lh[b] + lh[NBKT + b] + lh[2 * NBKT + b] + lh[3 * NBKT + b];
        if (s) atomicAdd(&ccnt[b], s);
    }
}

// ---------------- coarse offsets + sentinel ----------------
__global__ void scan_coarse_kernel(const int* __restrict__ ccnt,
                                   int* __restrict__ cofs, int* __restrict__ ccur,
                                   int* __restrict__ offsets, int E) {
    if (threadIdx.x == 0) {
        int run = 0;
        for (int b = 0; b < NBKT; ++b) { cofs[b] = run; ccur[b] = run; run += ccnt[b]; }
        cofs[NBKT] = run;              // == E
        offsets[N_NODES] = E;          // sentinel for prop kernels
    }
}

// ---------------- pass 1: coarse scatter, packed (local_dst<<17 | src) ----------------
__global__ __launch_bounds__(256) void coarse_scatter_kernel(const int* __restrict__ src,
                                                             const int* __restrict__ dst,
                                                             int* __restrict__ ccur,
                                                             unsigned int* __restrict__ tmp, int E) {
    __shared__ unsigned int buf[EPB];               // 16 KB
    __shared__ unsigned char bktA[EPB];             // 4 KB: bucket id per staged edge
    __shared__ int cnt[NBKT], lofs[NBKT], gofs[NBKT];
    int base = blockIdx.x * EPB;
    int n = E - base; if (n > EPB) n = EPB;

    for (int i = threadIdx.x; i < NBKT; i += 256) cnt[i] = 0;
    __syncthreads();

    unsigned int v[16]; int bk[16], loc[16];
    #pragma unroll
    for (int j = 0; j < 16; ++j) {
        int o = threadIdx.x + j * 256;
        bk[j] = -1;
        if (o < n) {
            int s = src[base + o];
            int d = dst[base + o];
            bk[j]  = d >> BSH;
            v[j]   = ((unsigned int)(d & (BNODES - 1)) << 17) | (unsigned int)s;
            loc[j] = atomicAdd(&cnt[bk[j]], 1);
        }
    }
    __syncthreads();
    if (threadIdx.x == 0) {
        int run = 0;
        for (int b = 0; b < NBKT; ++b) { lofs[b] = run; run += cnt[b]; }
    }
    __syncthreads();
    if (threadIdx.x < NBKT && cnt[threadIdx.x] > 0)
        gofs[threadIdx.x] = atomicAdd(&ccur[threadIdx.x], cnt[threadIdx.x]);
    __syncthreads();
    #pragma unroll
    for (int j = 0; j < 16; ++j)
        if (bk[j] >= 0) {
            int p = lofs[bk[j]] + loc[j];
            buf[p]  = v[j];
            bktA[p] = (unsigned char)bk[j];
        }
    __syncthreads();
    // dense run-out: consecutive i -> consecutive global addresses per bucket
    for (int i = threadIdx.x; i < n; i += 256) {
        int b = bktA[i];
        tmp[gofs[b] + (i - lofs[b])] = buf[i];
    }
}

// ---------------- pass 2: per-bucket LDS pipeline ----------------
__global__ __launch_bounds__(512) void bucket_kernel(const unsigned int* __restrict__ tmp,
                                                     const int* __restrict__ cofs,
                                                     int* __restrict__ offsets,
                                                     int* __restrict__ sorted_src,
                                                     float* __restrict__ dinv1,
                                                     float* __restrict__ dinv2, int N) {
    __shared__ int cnt[BNODES];   // histogram, then reused as absolute cursor
    __shared__ int sd[512];
    int b   = blockIdx.x;
    int tid = threadIdx.x;
    int beg = cofs[b], end = cofs[b + 1];

    for (int i = tid; i < BNODES; i += 512) cnt[i] = 0;
    __syncthreads();
    for (int i = beg + tid; i < end; i += 512)
        atomicAdd(&cnt[tmp[i] >> 17], 1);
    __syncthreads();

    int c0 = cnt[2 * tid], c1 = cnt[2 * tid + 1];
    int s  = c0 + c1;
    sd[tid] = s;
    __syncthreads();
    for (int off = 1; off < 512; off <<= 1) {
        int t = (tid >= off) ? sd[tid - off] : 0;
        __syncthreads();
        sd[tid] += t;
        __syncthreads();
    }
    int ex = sd[tid] - s;
    int g0 = beg + ex, g1 = beg + ex + c0;

    int node0 = b * BNODES + 2 * tid;
    if (node0 < N) {
        offsets[node0] = g0;
        dinv1[node0] = rsqrtf((float)(c0 + 1));
        dinv2[node0] = c0 ? rsqrtf((float)c0) : 0.0f;
    }
    if (node0 + 1 < N) {
        offsets[node0 + 1] = g1;
        dinv1[node0 + 1] = rsqrtf((float)(c1 + 1));
        dinv2[node0 + 1] = c1 ? rsqrtf((float)c1) : 0.0f;
    }
    __syncthreads();
    cnt[2 * tid] = g0;
    cnt[2 * tid + 1] = g1;
    __syncthreads();

    for (int i = beg + tid; i < end; i += 512) {
        unsigned int v = tmp[i];
        int p = atomicAdd(&cnt[v >> 17], 1);
        sorted_src[p] = (int)(v & 0x1FFFFu);
    }
}

// ---------------- MFMA GEMM: Xs = bf16((in_feat @ W1) * dinv1) ----------------
// D = W^T A^T via mfma_f32_16x16x32_bf16: one wave per 16-node tile.
// lane's node = tile*16 + (lane&15); output feats ct*16 + (lane>>4)*4 + r.
__global__ __launch_bounds__(256) void gemm_kernel(const float* __restrict__ A,
                                                   const uint4* __restrict__ wfrag,
                                                   const float* __restrict__ dinv1,
                                                   unsigned short* __restrict__ Xs, int nTiles) {
    int wid = blockIdx.x * 4 + (threadIdx.x >> 6);
    if (wid >= nTiles) return;
    int lane = threadIdx.x & 63;
    int lrow = lane & 15, lk = lane >> 4;

    // 16 W-frags (coalesced, L2-resident after first touch)
    short8 wf[16];
    #pragma unroll
    for (int i = 0; i < 16; ++i)
        wf[i] = *reinterpret_cast<const short8*>(&wfrag[i * 64 + lane]);

    int node = wid * 16 + lrow;
    const float4* ap = reinterpret_cast<const float4*>(A + (size_t)node * IN_F);

    // A-frags: lane supplies A^T[k = kc*32 + lk*8 + j][node], j=0..7 (consecutive k)
    short8 af[4];
    #pragma unroll
    for (int kc = 0; kc < 4; ++kc) {
        float4 x = ap[kc * 8 + lk * 2];
        float4 y = ap[kc * 8 + lk * 2 + 1];
        U16x8 u;
        u.us[0] = f2bf(x.x); u.us[1] = f2bf(x.y); u.us[2] = f2bf(x.z); u.us[3] = f2bf(x.w);
        u.us[4] = f2bf(y.x); u.us[5] = f2bf(y.y); u.us[6] = f2bf(y.z); u.us[7] = f2bf(y.w);
        af[kc] = u.v;
    }

    float dv = dinv1[node];
    #pragma unroll
    for (int ct = 0; ct < 4; ++ct) {
        floatx4 acc = {0.f, 0.f, 0.f, 0.f};
        acc = __builtin_amdgcn_mfma_f32_16x16x32_bf16(wf[ct * 4 + 0], af[0], acc, 0, 0, 0);
        acc = __builtin_amdgcn_mfma_f32_16x16x32_bf16(wf[ct * 4 + 1], af[1], acc, 0, 0, 0);
        acc = __builtin_amdgcn_mfma_f32_16x16x32_bf16(wf[ct * 4 + 2], af[2], acc, 0, 0, 0);
        acc = __builtin_amdgcn_mfma_f32_16x16x32_bf16(wf[ct * 4 + 3], af[3], acc, 0, 0, 0);
        uint2 o;
        o.x = pk2(acc[0] * dv, acc[1] * dv);
        o.y = pk2(acc[2] * dv, acc[3] * dv);
        *reinterpret_cast<uint2*>(Xs + (size_t)node * H_F + ct * 16 + lk * 4) = o;
    }
}

// ---------------- prop1 (gather, bf16 table) ----------------
// h1[d] = dinv1[d]*(sum Xs[s] + Xs[d]);  h1s[d] = h1[d]*dinv2[d]
__global__ __launch_bounds__(256) void prop1_kernel(const int* __restrict__ offsets,
                                                    const int* __restrict__ sorted_src,
                                                    const unsigned short* __restrict__ Xs,
                                                    const float* __restrict__ dinv1,
                                                    const float* __restrict__ dinv2,
                                                    unsigned short* __restrict__ h1,
                                                    unsigned short* __restrict__ h1s, int N) {
    int wid  = (blockIdx.x * blockDim.x + threadIdx.x) >> 6;
    int lane = threadIdx.x & 63;
    if (wid >= N) return;
    int d = wid;

    int beg = offsets[d], end = offsets[d + 1];
    float acc = 0.f;
    for (int i0 = beg; i0 < end; i0 += 64) {
        int cnt = end - i0; if (cnt > 64) cnt = 64;
        int s_l = 0;
        if (i0 + lane < end) s_l = sorted_src[i0 + lane];
        int j = 0;
        for (; j + 4 <= cnt; j += 4) {
            int s0 = __shfl(s_l, j + 0), s1 = __shfl(s_l, j + 1);
            int s2 = __shfl(s_l, j + 2), s3 = __shfl(s_l, j + 3);
            float x0 = bf2f(Xs[(size_t)s0 * H_F + lane]);
            float x1 = bf2f(Xs[(size_t)s1 * H_F + lane]);
            float x2 = bf2f(Xs[(size_t)s2 * H_F + lane]);
            float x3 = bf2f(Xs[(size_t)s3 * H_F + lane]);
            acc += x0; acc += x1; acc += x2; acc += x3;
        }
        for (; j < cnt; ++j) {
            int s = __shfl(s_l, j);
            acc += bf2f(Xs[(size_t)s * H_F + lane]);
        }
    }
    float dv = dinv1[d];
    float h  = dv * (acc + bf2f(Xs[(size_t)d * H_F + lane]));
    h1 [(size_t)d * H_F + lane] = f2bf(h);
    h1s[(size_t)d * H_F + lane] = f2bf(h * dinv2[d]);
}

// ---------------- prop2 (gather, bf16 h1s table) + alpha combine ----------------
__global__ __launch_bounds__(256) void prop2_kernel(const int* __restrict__ offsets,
                                                    const int* __restrict__ sorted_src,
                                                    const unsigned short* __restrict__ h1,
                                                    const unsigned short* __restrict__ h1s,
                                                    const float* __restrict__ dinv2,
                                                    const float* __restrict__ alphas,
                                                    float* __restrict__ out, int N) {
    int wid  = (blockIdx.x * blockDim.x + threadIdx.x) >> 6;
    int lane = threadIdx.x & 63;
    if (wid >= N) return;
    int d = wid;

    float e0 = expf(alphas[0]), e1 = expf(alphas[1]);
    float a0 = e0 / (e0 + e1), a1 = e1 / (e0 + e1);

    int beg = offsets[d], end = offsets[d + 1];
    float acc = 0.f;
    for (int i0 = beg; i0 < end; i0 += 64) {
        int cnt = end - i0; if (cnt > 64) cnt = 64;
        int s_l = 0;
        if (i0 + lane < end) s_l = sorted_src[i0 + lane];
        int j = 0;
        for (; j + 4 <= cnt; j += 4) {
            int s0 = __shfl(s_l, j + 0), s1 = __shfl(s_l, j + 1);
            int s2 = __shfl(s_l, j + 2), s3 = __shfl(s_l, j + 3);
            float x0 = bf2f(h1s[(size_t)s0 * H_F + lane]);
            float x1 = bf2f(h1s[(size_t)s1 * H_F + lane]);
            float x2 = bf2f(h1s[(size_t)s2 * H_F + lane]);
            float x3 = bf2f(h1s[(size_t)s3 * H_F + lane]);
            acc += x0; acc += x1; acc += x2; acc += x3;
        }
        for (; j < cnt; ++j) {
            int s = __shfl(s_l, j);
            acc += bf2f(h1s[(size_t)s * H_F + lane]);
        }
    }
    out[(size_t)d * H_F + lane] = a0 * bf2f(h1[(size_t)d * H_F + lane]) + a1 * dinv2[d] * acc;
}

extern "C" void kernel_launch(void* const* d_in, const int* in_sizes, int n_in,
                              void* d_out, int out_size, void* d_ws, size_t ws_size,
                              hipStream_t stream) {
    const int*   edge_index = (const int*)d_in[0];   // [2, E]
    const float* in_feat    = (const float*)d_in[1]; // [N, 128]
    const float* W1         = (const float*)d_in[2]; // [128, 64]
    const float* alphas     = (const float*)d_in[3]; // [2]
    float*       out        = (float*)d_out;         // [N, 64]

    const int* src = edge_index;
    const int* dst = edge_index + N_EDGES;

    // workspace layout (bf16 tables: N*64*2 = 12.8 MB each)
    char* ws = (char*)d_ws;
    size_t tabBytes = (size_t)N_NODES * H_F * 2;
    unsigned short* Xs  = (unsigned short*)(ws);                 // 12.8 MB
    unsigned int*   tmp = (unsigned int*)(ws);                   // 6.4 MB — aliases Xs (dead until gemm)
    unsigned short* h1  = (unsigned short*)(ws + tabBytes);      // 12.8 MB
    unsigned short* h1s = (unsigned short*)(ws + 2 * tabBytes);  // 12.8 MB
    char* p = ws + 3 * tabBytes;
    int*   sorted = (int*)p;   p += (size_t)N_EDGES * 4;         // 6.4 MB
    int*   offs   = (int*)p;   p += (size_t)(N_NODES + 4) * 4;
    float* dinv1  = (float*)p; p += (size_t)N_NODES * 4;
    float* dinv2  = (float*)p; p += (size_t)N_NODES * 4;
    int*   ccnt   = (int*)p;   p += (size_t)NBKT * 4;
    int*   cofs   = (int*)p;   p += (size_t)(NBKT + 1) * 4;
    int*   ccur   = (int*)p;   p += (size_t)NBKT * 4;
    unsigned int* wfrag = (unsigned int*)p; p += 8192 * 4;       // 32 KB packed W frags

    hipMemsetAsync(ccnt, 0, (size_t)NBKT * sizeof(int), stream);

    wpack_kernel<<<32, 256, 0, stream>>>(W1, wfrag);
    hist_kernel<<<512, 256, 0, stream>>>(dst, ccnt, N_EDGES);
    scan_coarse_kernel<<<1, 64, 0, stream>>>(ccnt, cofs, ccur, offs, N_EDGES);
    coarse_scatter_kernel<<<(N_EDGES + EPB - 1) / EPB, 256, 0, stream>>>(src, dst, ccur, tmp, N_EDGES);
    bucket_kernel<<<NBKT, 512, 0, stream>>>(tmp, cofs, offs, sorted, dinv1, dinv2, N_NODES);

    // gemm after bucket_kernel (tmp aliases Xs; needs dinv1)
    int nTiles = N_NODES / 16;                        // 6250
    gemm_kernel<<<(nTiles + 3) / 4, 256, 0, stream>>>(in_feat, (const uint4*)wfrag, dinv1, Xs, nTiles);

    int nblocks = (N_NODES * 64 + 255) / 256; // one wave per node
    prop1_kernel<<<nblocks, 256, 0, stream>>>(offs, sorted, Xs, dinv1, dinv2, h1, h1s, N_NODES);
    prop2_kernel<<<nblocks, 256, 0, stream>>>(offs, sorted, h1, h1s, dinv2, alphas, out, N_NODES);
}